// Round 1
// baseline (152.962 us; speedup 1.0000x reference)
//
#include <hip/hip_runtime.h>
#include <math.h>

// Problem constants
constexpr int NPG  = 64;      // nodes per graph
constexpr int EPG  = 512;     // edges per graph
constexpr int ETOT = 131072;  // total edges

// ws layout (float offsets)
constexpr size_t TAB_Q  = 0;
constexpr size_t TAB_K  = 1024;
constexpr size_t TAB_V  = 2048;
constexpr size_t TAB_S  = 3072;   // 4*64
constexpr size_t TAB_LG = 3328;   // 64
constexpr size_t OFF_H1 = 4096;
constexpr size_t OFF_Q2 = OFF_H1 + 16384ull * 64;
constexpr size_t OFF_K2 = OFF_Q2 + 16384ull * 256;
constexpr size_t OFF_V2 = OFF_K2 + 16384ull * 256;
constexpr size_t OFF_S2 = OFF_V2 + 16384ull * 256;
constexpr size_t OFF_H2 = OFF_S2 + 16384ull * 64;
constexpr size_t OFF_A  = OFF_H2 + 16384ull * 64;
constexpr size_t OFF_B  = OFF_A  + 16384ull * 64;

// ---------------------------------------------------------------------------
// Kernel A: time embedding + layer-1 class tables (x is one-hot(4), temb is
// node-constant => q1/k1/v1/skip1 take only 4 distinct rows; logits take 64
// distinct values lg[dst_class][src_class][head]).
// ---------------------------------------------------------------------------
__global__ __launch_bounds__(256) void k_tables(
    const int* __restrict__ t_ptr,
    const float* __restrict__ Wt,  const float* __restrict__ bt,
    const float* __restrict__ Wq1, const float* __restrict__ bq1,
    const float* __restrict__ Wk1, const float* __restrict__ bk1,
    const float* __restrict__ Wv1, const float* __restrict__ bv1,
    const float* __restrict__ Ws1, const float* __restrict__ bs1,
    float* __restrict__ ws)
{
    __shared__ float se[16], temb[16];
    __shared__ float q1t[4][256], k1t[4][256], v1t[4][256], s1t[4][64];
    const int t = threadIdx.x;

    if (t < 8) {
        float tv = (float)(*t_ptr) * 0.01f;        // t / T_STEPS
        float scale = logf(10000.0f) / 7.0f;       // half=8 -> /(half-1)
        float e = tv * expf(-(float)t * scale);
        se[t]     = sinf(e);
        se[t + 8] = cosf(e);
    }
    __syncthreads();
    if (t < 16) {
        float acc = bt[t];
        for (int i = 0; i < 16; i++) acc += se[i] * Wt[i * 16 + t];
        temb[t] = acc;
    }
    __syncthreads();
    {
        const int o = t;  // 0..255
        float tq = 0.f, tk = 0.f, tv = 0.f;
        for (int d = 0; d < 16; d++) {
            float td = temb[d];
            tq += td * Wq1[(4 + d) * 256 + o];
            tk += td * Wk1[(4 + d) * 256 + o];
            tv += td * Wv1[(4 + d) * 256 + o];
        }
        for (int c = 0; c < 4; c++) {
            q1t[c][o] = Wq1[c * 256 + o] + tq + bq1[o];
            k1t[c][o] = Wk1[c * 256 + o] + tk + bk1[o];
            v1t[c][o] = Wv1[c * 256 + o] + tv + bv1[o];
        }
        if (o < 64) {
            float ts = 0.f;
            for (int d = 0; d < 16; d++) ts += temb[d] * Ws1[(4 + d) * 64 + o];
            for (int c = 0; c < 4; c++) s1t[c][o] = Ws1[c * 64 + o] + ts + bs1[o];
        }
    }
    __syncthreads();
    for (int idx = t; idx < 1024; idx += 256) {
        int c = idx >> 8, o = idx & 255;
        ws[TAB_Q + idx] = q1t[c][o];
        ws[TAB_K + idx] = k1t[c][o];
        ws[TAB_V + idx] = v1t[c][o];
    }
    ws[TAB_S + t] = s1t[t >> 6][t & 63];
    if (t < 64) {
        int cd = t >> 4, cs = (t >> 2) & 3, h = t & 3;
        float acc = 0.f;
        for (int d = 0; d < 64; d++) acc += q1t[cd][h * 64 + d] * k1t[cs][h * 64 + d];
        ws[TAB_LG + t] = acc * 0.125f;   // / sqrt(64)
    }
}

// ---------------------------------------------------------------------------
// Kernel B: layer 1 = per-node histogram of incoming src classes -> softmax
// over <=4 distinct logits -> combine 4 v-table rows + skip, relu.
// One block per graph (edges are grouped 512/graph, nodes 64/graph).
// ---------------------------------------------------------------------------
__global__ __launch_bounds__(256) void k_layer1(
    const float* __restrict__ x, const int* __restrict__ ei,
    const float* __restrict__ ws, float* __restrict__ h1)
{
    __shared__ float v1t[4][256];
    __shared__ float s1t[4][64];
    __shared__ float lg[64];
    __shared__ int   cls[64];
    __shared__ int   cnt[64][4];
    __shared__ float alpha[64][16];  // [node][h*4+c], includes 0.25 head-mean
    const int g = blockIdx.x, t = threadIdx.x;

    for (int i = t; i < 1024; i += 256) v1t[i >> 8][i & 255] = ws[TAB_V + i];
    s1t[t >> 6][t & 63] = ws[TAB_S + t];
    if (t < 64) lg[t] = ws[TAB_LG + t];
    if (t < 64) {
        const float* xr = x + (size_t)(g * 64 + t) * 4;
        int c = 0;
        if (xr[1] > 0.5f) c = 1;
        if (xr[2] > 0.5f) c = 2;
        if (xr[3] > 0.5f) c = 3;
        cls[t] = c;
    }
    cnt[t >> 2][t & 3] = 0;
    __syncthreads();

    for (int e = t; e < EPG; e += 256) {
        int ge = g * EPG + e;
        int ls = ei[ge] - g * 64;
        int ld = ei[ETOT + ge] - g * 64;
        atomicAdd(&cnt[ld][cls[ls]], 1);
    }
    __syncthreads();

    {
        int n = t >> 2, h = t & 3;
        int cd = cls[n];
        int   c[4]; float l[4];
        for (int cc = 0; cc < 4; cc++) {
            c[cc] = cnt[n][cc];
            l[cc] = lg[cd * 16 + cc * 4 + h];
        }
        float m = -1e30f;
        for (int cc = 0; cc < 4; cc++) if (c[cc] > 0) m = fmaxf(m, l[cc]);
        float e[4]; float den = 0.f;
        for (int cc = 0; cc < 4; cc++) {
            e[cc] = (c[cc] > 0) ? (float)c[cc] * expf(l[cc] - m) : 0.f;
            den += e[cc];
        }
        float inv = (den > 0.f) ? 0.25f / den : 0.f;
        for (int cc = 0; cc < 4; cc++) alpha[n][h * 4 + cc] = e[cc] * inv;
    }
    __syncthreads();

    {
        int n = t >> 2, d0 = (t & 3) * 16;
        int cd = cls[n];
        float a[16];
        for (int q = 0; q < 16; q++) a[q] = alpha[n][q];
        float* dst = h1 + (size_t)(g * 64 + n) * 64 + d0;
        for (int dd = 0; dd < 16; dd++) {
            int d = d0 + dd;
            float acc = s1t[cd][d];
            #pragma unroll
            for (int h = 0; h < 4; h++)
                #pragma unroll
                for (int c = 0; c < 4; c++)
                    acc += a[h * 4 + c] * v1t[c][h * 64 + d];
            dst[dd] = fmaxf(acc, 0.f);
        }
    }
}

// ---------------------------------------------------------------------------
// Kernel C: layer-2 projections: [16384,64] @ [64,{256,256,256,64}] + bias.
// q gets pre-scaled by 1/sqrt(64). grid (256 M-tiles, 13 col-chunks).
// ---------------------------------------------------------------------------
__global__ __launch_bounds__(256) void k_qkvs(
    const float* __restrict__ h1,
    const float* __restrict__ Wq, const float* __restrict__ bq,
    const float* __restrict__ Wk, const float* __restrict__ bk,
    const float* __restrict__ Wv, const float* __restrict__ bv,
    const float* __restrict__ Wsk, const float* __restrict__ bsk,
    float* __restrict__ ws)
{
    __shared__ __align__(16) float As[64 * 68];
    __shared__ __align__(16) float Bs[64 * 68];
    const int g = blockIdx.x, ci = blockIdx.y, t = threadIdx.x;

    const float *W, *bias; size_t obase; int ldo, ldw, cb; float scale;
    if (ci < 4)       { W = Wq;  bias = bq;  obase = OFF_Q2; ldo = 256; ldw = 256; cb = ci * 64;        scale = 0.125f; }
    else if (ci < 8)  { W = Wk;  bias = bk;  obase = OFF_K2; ldo = 256; ldw = 256; cb = (ci - 4) * 64;  scale = 1.f; }
    else if (ci < 12) { W = Wv;  bias = bv;  obase = OFF_V2; ldo = 256; ldw = 256; cb = (ci - 8) * 64;  scale = 1.f; }
    else              { W = Wsk; bias = bsk; obase = OFF_S2; ldo = 64;  ldw = 64;  cb = 0;              scale = 1.f; }

    for (int i = t; i < 1024; i += 256) {
        int r = i >> 4, c4 = (i & 15) * 4;
        *(float4*)&As[r * 68 + c4] = *(const float4*)&h1[(size_t)(g * 64 + r) * 64 + c4];
        *(float4*)&Bs[r * 68 + c4] = *(const float4*)&W[(size_t)r * ldw + cb + c4];
    }
    __syncthreads();

    const int ty = t >> 4, tx = t & 15;
    float acc[4][4] = {};
    for (int k = 0; k < 64; k += 4) {
        float4 a[4], b[4];
        #pragma unroll
        for (int r = 0; r < 4; r++)  a[r] = *(const float4*)&As[(ty * 4 + r) * 68 + k];
        #pragma unroll
        for (int kk = 0; kk < 4; kk++) b[kk] = *(const float4*)&Bs[(k + kk) * 68 + tx * 4];
        #pragma unroll
        for (int r = 0; r < 4; r++) {
            float a0 = a[r].x, a1 = a[r].y, a2 = a[r].z, a3 = a[r].w;
            acc[r][0] += a0 * b[0].x + a1 * b[1].x + a2 * b[2].x + a3 * b[3].x;
            acc[r][1] += a0 * b[0].y + a1 * b[1].y + a2 * b[2].y + a3 * b[3].y;
            acc[r][2] += a0 * b[0].z + a1 * b[1].z + a2 * b[2].z + a3 * b[3].z;
            acc[r][3] += a0 * b[0].w + a1 * b[1].w + a2 * b[2].w + a3 * b[3].w;
        }
    }
    #pragma unroll
    for (int r = 0; r < 4; r++) {
        size_t row = (size_t)(g * 64 + ty * 4 + r);
        float4 o;
        o.x = (acc[r][0] + bias[cb + tx * 4 + 0]) * scale;
        o.y = (acc[r][1] + bias[cb + tx * 4 + 1]) * scale;
        o.z = (acc[r][2] + bias[cb + tx * 4 + 2]) * scale;
        o.w = (acc[r][3] + bias[cb + tx * 4 + 3]) * scale;
        *(float4*)&ws[obase + row * ldo + cb + tx * 4] = o;
    }
}

// ---------------------------------------------------------------------------
// Kernel D: layer-2 attention, dense per graph. C[i][j] = multi-edge count
// (exactly reproduces segment softmax incl. duplicates). One block/graph.
// ---------------------------------------------------------------------------
__global__ __launch_bounds__(512) void k_attn2(const int* __restrict__ ei,
                                               float* __restrict__ ws)
{
    __shared__ __align__(16) float Qs[64 * 68];   // Q, then reused for V
    __shared__ __align__(16) float Ks[64 * 68];
    __shared__ __align__(16) float Ss[64 * 68];
    __shared__ int   Cc[2048];                    // ushort-packed counts
    __shared__ float invden[64];
    const int g = blockIdx.x, t = threadIdx.x;
    const float* q2 = ws + OFF_Q2;
    const float* k2 = ws + OFF_K2;
    const float* v2 = ws + OFF_V2;
    const float* s2 = ws + OFF_S2;
    float* h2 = ws + OFF_H2;

    for (int i = t; i < 2048; i += 512) Cc[i] = 0;
    __syncthreads();
    {
        int ge = g * EPG + t;  // 512 threads == 512 edges
        int ls = ei[ge] - g * 64;
        int ld = ei[ETOT + ge] - g * 64;
        int idx = ld * 64 + ls;
        atomicAdd(&Cc[idx >> 1], 1 << ((idx & 1) * 16));
    }
    __syncthreads();

    const int i8 = t >> 3;       // row 0..63
    const int sub = t & 7;
    float hacc[8] = {0, 0, 0, 0, 0, 0, 0, 0};

    for (int h = 0; h < 4; h++) {
        for (int i = t; i < 1024; i += 512) {
            int n = i >> 4, c4 = (i & 15) * 4;
            *(float4*)&Qs[n * 68 + c4] = *(const float4*)&q2[(size_t)(g * 64 + n) * 256 + h * 64 + c4];
            *(float4*)&Ks[n * 68 + c4] = *(const float4*)&k2[(size_t)(g * 64 + n) * 256 + h * 64 + c4];
        }
        __syncthreads();
        {   // S = Q K^T  (q pre-scaled) : thread handles (i8, j = jb..jb+7)
            int jb = sub * 8;
            float acc[8] = {0, 0, 0, 0, 0, 0, 0, 0};
            for (int k = 0; k < 64; k += 4) {
                float4 qv = *(const float4*)&Qs[i8 * 68 + k];
                #pragma unroll
                for (int jj = 0; jj < 8; jj++) {
                    float4 kv = *(const float4*)&Ks[(jb + jj) * 68 + k];
                    acc[jj] += qv.x * kv.x + qv.y * kv.y + qv.z * kv.z + qv.w * kv.w;
                }
            }
            *(float4*)&Ss[i8 * 68 + jb]     = make_float4(acc[0], acc[1], acc[2], acc[3]);
            *(float4*)&Ss[i8 * 68 + jb + 4] = make_float4(acc[4], acc[5], acc[6], acc[7]);
        }
        __syncthreads();
        // V load (into Qs; Q is dead) + row softmax with counts
        for (int i = t; i < 1024; i += 512) {
            int n = i >> 4, c4 = (i & 15) * 4;
            *(float4*)&Qs[n * 68 + c4] = *(const float4*)&v2[(size_t)(g * 64 + n) * 256 + h * 64 + c4];
        }
        {
            int jb = sub * 8;
            int cv[8];
            float m = -1e30f;
            #pragma unroll
            for (int jj = 0; jj < 8; jj++) {
                int idx = i8 * 64 + jb + jj;
                cv[jj] = (Cc[idx >> 1] >> ((idx & 1) * 16)) & 0xffff;
                if (cv[jj] > 0) m = fmaxf(m, Ss[i8 * 68 + jb + jj]);
            }
            for (int off = 1; off < 8; off <<= 1) m = fmaxf(m, __shfl_xor(m, off, 8));
            float den = 0.f;
            #pragma unroll
            for (int jj = 0; jj < 8; jj++) {
                float p = 0.f;
                if (cv[jj] > 0) p = (float)cv[jj] * expf(Ss[i8 * 68 + jb + jj] - m);
                Ss[i8 * 68 + jb + jj] = p;
                den += p;
            }
            for (int off = 1; off < 8; off <<= 1) den += __shfl_xor(den, off, 8);
            if (sub == 0) invden[i8] = (den > 0.f) ? 1.f / den : 0.f;
        }
        __syncthreads();
        {   // PV: thread (i8, d0 = sub*8): agg[i8][d0..d0+7]
            int d0 = sub * 8;
            float acc[8] = {0, 0, 0, 0, 0, 0, 0, 0};
            for (int j = 0; j < 64; j++) {
                float p = Ss[i8 * 68 + j];
                float4 va = *(const float4*)&Qs[j * 68 + d0];
                float4 vb = *(const float4*)&Qs[j * 68 + d0 + 4];
                acc[0] += p * va.x; acc[1] += p * va.y; acc[2] += p * va.z; acc[3] += p * va.w;
                acc[4] += p * vb.x; acc[5] += p * vb.y; acc[6] += p * vb.z; acc[7] += p * vb.w;
            }
            float inv = invden[i8];
            #pragma unroll
            for (int q = 0; q < 8; q++) hacc[q] += acc[q] * inv;
        }
        __syncthreads();
    }
    {   // h2 = relu(mean_heads + skip)
        int d0 = sub * 8;
        const float* sk = s2 + (size_t)(g * 64 + i8) * 64 + d0;
        float* dst = h2 + (size_t)(g * 64 + i8) * 64 + d0;
        #pragma unroll
        for (int q = 0; q < 8; q++) dst[q] = fmaxf(0.25f * hacc[q] + sk[q], 0.f);
    }
}

// ---------------------------------------------------------------------------
// Kernel E: node logits + edge-MLP factorization A = h2@We1_top + b_e1,
// B = h2@We1_bot. One block per graph.
// ---------------------------------------------------------------------------
__device__ __forceinline__ void gemm_tile(const float* As, const float* Bs,
                                          int ty, int tx, float acc[4][4])
{
    for (int k = 0; k < 64; k += 4) {
        float4 a[4], b[4];
        #pragma unroll
        for (int r = 0; r < 4; r++)  a[r] = *(const float4*)&As[(ty * 4 + r) * 68 + k];
        #pragma unroll
        for (int kk = 0; kk < 4; kk++) b[kk] = *(const float4*)&Bs[(k + kk) * 68 + tx * 4];
        #pragma unroll
        for (int r = 0; r < 4; r++) {
            float a0 = a[r].x, a1 = a[r].y, a2 = a[r].z, a3 = a[r].w;
            acc[r][0] += a0 * b[0].x + a1 * b[1].x + a2 * b[2].x + a3 * b[3].x;
            acc[r][1] += a0 * b[0].y + a1 * b[1].y + a2 * b[2].y + a3 * b[3].y;
            acc[r][2] += a0 * b[0].z + a1 * b[1].z + a2 * b[2].z + a3 * b[3].z;
            acc[r][3] += a0 * b[0].w + a1 * b[1].w + a2 * b[2].w + a3 * b[3].w;
        }
    }
}

__global__ __launch_bounds__(256) void k_head(
    const float* __restrict__ Wn, const float* __restrict__ bn,
    const float* __restrict__ We1, const float* __restrict__ be1,
    float* __restrict__ out, float* __restrict__ ws)
{
    __shared__ __align__(16) float hs[64 * 68];
    __shared__ __align__(16) float Bs[64 * 68];
    __shared__ float WnS[256];
    const int g = blockIdx.x, t = threadIdx.x;
    const float* h2 = ws + OFF_H2;
    float* Aout = ws + OFF_A;
    float* Bout = ws + OFF_B;

    for (int i = t; i < 1024; i += 256) {
        int n = i >> 4, c4 = (i & 15) * 4;
        *(float4*)&hs[n * 68 + c4] = *(const float4*)&h2[(size_t)(g * 64 + n) * 64 + c4];
        *(float4*)&Bs[n * 68 + c4] = *(const float4*)&We1[(size_t)n * 64 + c4];  // top half
    }
    WnS[t] = Wn[t];
    __syncthreads();

    {   // node logits
        int n = t >> 2, c = t & 3;
        float acc = bn[c];
        for (int k = 0; k < 64; k++) acc += hs[n * 68 + k] * WnS[k * 4 + c];
        out[(size_t)(g * 64 + n) * 4 + c] = acc;
    }
    const int ty = t >> 4, tx = t & 15;
    {   // A pass
        float acc[4][4] = {};
        gemm_tile(hs, Bs, ty, tx, acc);
        #pragma unroll
        for (int r = 0; r < 4; r++) {
            size_t row = (size_t)(g * 64 + ty * 4 + r);
            float4 o;
            o.x = acc[r][0] + be1[tx * 4 + 0];
            o.y = acc[r][1] + be1[tx * 4 + 1];
            o.z = acc[r][2] + be1[tx * 4 + 2];
            o.w = acc[r][3] + be1[tx * 4 + 3];
            *(float4*)&Aout[row * 64 + tx * 4] = o;
        }
    }
    __syncthreads();
    for (int i = t; i < 1024; i += 256) {
        int n = i >> 4, c4 = (i & 15) * 4;
        *(float4*)&Bs[n * 68 + c4] = *(const float4*)&We1[(size_t)(64 + n) * 64 + c4];  // bottom
    }
    __syncthreads();
    {   // B pass
        float acc[4][4] = {};
        gemm_tile(hs, Bs, ty, tx, acc);
        #pragma unroll
        for (int r = 0; r < 4; r++) {
            size_t row = (size_t)(g * 64 + ty * 4 + r);
            *(float4*)&Bout[row * 64 + tx * 4] =
                make_float4(acc[r][0], acc[r][1], acc[r][2], acc[r][3]);
        }
    }
}

// ---------------------------------------------------------------------------
// Kernel F: edge logits: relu(A_i + B_j) @ W_e2 + b_e2 for all 64x64 pairs.
// One block (512 thr = 8 waves) per graph; wave handles 8 rows i, lane = j.
// ---------------------------------------------------------------------------
__global__ __launch_bounds__(512) void k_edge(
    const float* __restrict__ We2, const float* __restrict__ be2,
    const float* __restrict__ wsc, float* __restrict__ out_edges)
{
    __shared__ __align__(16) float Al[64 * 68];
    __shared__ __align__(16) float Bl[64 * 68];
    __shared__ __align__(16) float w0s[64];
    __shared__ __align__(16) float w1s[64];
    const int g = blockIdx.x, t = threadIdx.x;
    const float* A  = wsc + OFF_A;
    const float* Bv = wsc + OFF_B;

    for (int i = t; i < 1024; i += 512) {
        int n = i >> 4, c4 = (i & 15) * 4;
        *(float4*)&Al[n * 68 + c4] = *(const float4*)&A[(size_t)(g * 64 + n) * 64 + c4];
        *(float4*)&Bl[n * 68 + c4] = *(const float4*)&Bv[(size_t)(g * 64 + n) * 64 + c4];
    }
    if (t < 64) { w0s[t] = We2[t * 2]; w1s[t] = We2[t * 2 + 1]; }
    __syncthreads();

    const int w = t >> 6, j = t & 63;
    float acc0[8], acc1[8];
    const float b0 = be2[0], b1 = be2[1];
    #pragma unroll
    for (int ii = 0; ii < 8; ii++) { acc0[ii] = b0; acc1[ii] = b1; }

    for (int kb = 0; kb < 4; kb++) {
        const int k0 = kb * 16;
        float bj[16], wa[16], wb[16];
        #pragma unroll
        for (int q = 0; q < 16; q += 4) {
            float4 bv4 = *(const float4*)&Bl[j * 68 + k0 + q];
            bj[q] = bv4.x; bj[q + 1] = bv4.y; bj[q + 2] = bv4.z; bj[q + 3] = bv4.w;
            float4 w04 = *(const float4*)&w0s[k0 + q];
            wa[q] = w04.x; wa[q + 1] = w04.y; wa[q + 2] = w04.z; wa[q + 3] = w04.w;
            float4 w14 = *(const float4*)&w1s[k0 + q];
            wb[q] = w14.x; wb[q + 1] = w14.y; wb[q + 2] = w14.z; wb[q + 3] = w14.w;
        }
        #pragma unroll
        for (int ii = 0; ii < 8; ii++) {
            const int i = w * 8 + ii;
            #pragma unroll
            for (int q = 0; q < 16; q += 4) {
                float4 a4 = *(const float4*)&Al[i * 68 + k0 + q];
                float s;
                s = fmaxf(a4.x + bj[q + 0], 0.f); acc0[ii] += s * wa[q + 0]; acc1[ii] += s * wb[q + 0];
                s = fmaxf(a4.y + bj[q + 1], 0.f); acc0[ii] += s * wa[q + 1]; acc1[ii] += s * wb[q + 1];
                s = fmaxf(a4.z + bj[q + 2], 0.f); acc0[ii] += s * wa[q + 2]; acc1[ii] += s * wb[q + 2];
                s = fmaxf(a4.w + bj[q + 3], 0.f); acc0[ii] += s * wa[q + 3]; acc1[ii] += s * wb[q + 3];
            }
        }
    }
    float2* oe = (float2*)out_edges;
    #pragma unroll
    for (int ii = 0; ii < 8; ii++) {
        const int i = w * 8 + ii;
        oe[(size_t)(g * 64 + i) * 64 + j] = make_float2(acc0[ii], acc1[ii]);
    }
}

// ---------------------------------------------------------------------------
extern "C" void kernel_launch(void* const* d_in, const int* in_sizes, int n_in,
                              void* d_out, int out_size, void* d_ws, size_t ws_size,
                              hipStream_t stream)
{
    const float* x    = (const float*)d_in[0];
    const int*   ei   = (const int*)d_in[1];
    // d_in[2] = batch (unused; graphs are equal-sized & contiguous)
    const int*   tptr = (const int*)d_in[3];
    const float* Wt   = (const float*)d_in[4];
    const float* bt   = (const float*)d_in[5];
    const float* Wq1  = (const float*)d_in[6];
    const float* bq1  = (const float*)d_in[7];
    const float* Wk1  = (const float*)d_in[8];
    const float* bk1  = (const float*)d_in[9];
    const float* Wv1  = (const float*)d_in[10];
    const float* bv1  = (const float*)d_in[11];
    const float* Ws1  = (const float*)d_in[12];
    const float* bs1  = (const float*)d_in[13];
    const float* Wq2  = (const float*)d_in[14];
    const float* bq2  = (const float*)d_in[15];
    const float* Wk2  = (const float*)d_in[16];
    const float* bk2  = (const float*)d_in[17];
    const float* Wv2  = (const float*)d_in[18];
    const float* bv2  = (const float*)d_in[19];
    const float* Ws2  = (const float*)d_in[20];
    const float* bs2  = (const float*)d_in[21];
    const float* Wn   = (const float*)d_in[22];
    const float* bn   = (const float*)d_in[23];
    const float* We1  = (const float*)d_in[24];
    const float* be1  = (const float*)d_in[25];
    const float* We2  = (const float*)d_in[26];
    const float* be2  = (const float*)d_in[27];

    float* ws  = (float*)d_ws;
    float* out = (float*)d_out;

    k_tables<<<1, 256, 0, stream>>>(tptr, Wt, bt, Wq1, bq1, Wk1, bk1, Wv1, bv1, Ws1, bs1, ws);
    k_layer1<<<256, 256, 0, stream>>>(x, ei, ws, ws + OFF_H1);
    k_qkvs<<<dim3(256, 13), 256, 0, stream>>>(ws + OFF_H1, Wq2, bq2, Wk2, bk2, Wv2, bv2, Ws2, bs2, ws);
    k_attn2<<<256, 512, 0, stream>>>(ei, ws);
    k_head<<<256, 256, 0, stream>>>(Wn, bn, We1, be1, out, ws);
    k_edge<<<256, 512, 0, stream>>>(We2, be2, ws, out + 65536);
}